// Round 17
// baseline (346.880 us; speedup 1.0000x reference)
//
#include <hip/hip_runtime.h>
#include <hip/hip_bf16.h>
#include <hip/hip_fp8.h>

#define N_NODES 100000
#define N_EDGES 320000
#define HID 256
#define NE 128

typedef __attribute__((ext_vector_type(4))) float f32x4;
typedef long long i64v;

__device__ inline unsigned char f2fp8(float f) { return __hip_fp8_e4m3(f).__x; }
__device__ inline float fp82f(unsigned char b) {
    __hip_fp8_e4m3 h; h.__x = b; return (float)h;
}
__device__ inline unsigned int pack_fp8x4(float a, float b, float c, float d) {
    return (unsigned)f2fp8(a) | ((unsigned)f2fp8(b) << 8) |
           ((unsigned)f2fp8(c) << 16) | ((unsigned)f2fp8(d) << 24);
}

// ---------------------------------------------------------------------------
// Weight prep: sage + head weights fp32 -> fp8 [n][k].  Zeroes deg/total.
// ---------------------------------------------------------------------------
__global__ __launch_bounds__(256) void k_prep(
    const float* __restrict__ Wl, const float* __restrict__ Wr,
    const float* __restrict__ W0,
    unsigned char* __restrict__ Wt8, unsigned char* __restrict__ Wh8,
    int* __restrict__ deg, int* __restrict__ total)
{
    int t = blockIdx.x * 256 + threadIdx.x;
    const int total_sage = 3 * 256 * 512;
    if (t < total_sage) {
        int l = t >> 17;
        int rem = t & 131071;
        int n = rem >> 9;
        int k = rem & 511;
        const float* Wsrc = (k < 256) ? (Wl + (size_t)l * 65536)
                                      : (Wr + (size_t)l * 65536);
        Wt8[t] = f2fp8(Wsrc[(k & 255) * 256 + n]);
    } else {
        int u = t - total_sage;
        if (u < 65536) {
            int n = u >> 8, k = u & 255;
            Wh8[u] = f2fp8(W0[k * 256 + n]);
        }
    }
    if (t < N_NODES) deg[t] = 0;
    if (t == 0) *total = 0;
}

// ---------------------------------------------------------------------------
// Init: x0 in fp8 (row = 256B: [emb 0..127 | attr 128..255]).
// 16 thr/node x 8 cols, uint2 stores.  Tail ranges: output tail + histogram.
// ---------------------------------------------------------------------------
__global__ __launch_bounds__(256) void k_init(
    const float* __restrict__ node_attr,
    const float* __restrict__ node_emb,
    const float* __restrict__ net_W, const float* __restrict__ net_b,
    const float* __restrict__ dev_W, const float* __restrict__ dev_b,
    const float* __restrict__ pin_emb,
    const int*   __restrict__ node_type,
    const float* __restrict__ y, const float* __restrict__ b1,
    const int*   __restrict__ edge_index, int* __restrict__ deg,
    float* __restrict__ out,
    unsigned char* __restrict__ x)
{
    int t = blockIdx.x * 256 + threadIdx.x;
    if (t < N_NODES * 16) {
        int n  = t >> 4;
        int c8 = (t & 15) * 8;
        int ty = node_type[n];
        float4 e0 = *(const float4*)(node_emb + ty * NE + c8);
        float4 e1 = *(const float4*)(node_emb + ty * NE + c8 + 4);
        float4 a0, a1;
        if (ty == 0 || ty == 1) {
            const float* W = (ty == 0) ? net_W : dev_W;
            const float* b = (ty == 0) ? net_b : dev_b;
            a0 = *(const float4*)(b + c8);
            a1 = *(const float4*)(b + c8 + 4);
            const float* ar = node_attr + (size_t)n * 17;
            #pragma unroll
            for (int k = 0; k < 17; ++k) {
                float av = ar[k];
                float4 w0 = *(const float4*)(W + k * NE + c8);
                float4 w1 = *(const float4*)(W + k * NE + c8 + 4);
                a0.x += av * w0.x; a0.y += av * w0.y;
                a0.z += av * w0.z; a0.w += av * w0.w;
                a1.x += av * w1.x; a1.y += av * w1.y;
                a1.z += av * w1.z; a1.w += av * w1.w;
            }
        } else if (ty == 2) {
            int idx = (int)node_attr[(size_t)n * 17];
            a0 = *(const float4*)(pin_emb + idx * NE + c8);
            a1 = *(const float4*)(pin_emb + idx * NE + c8 + 4);
        } else {
            a0.x = a0.y = a0.z = a0.w = 0.0f;
            a1 = a0;
        }
        uint2 ev = {pack_fp8x4(e0.x, e0.y, e0.z, e0.w),
                    pack_fp8x4(e1.x, e1.y, e1.z, e1.w)};
        uint2 av = {pack_fp8x4(a0.x, a0.y, a0.z, a0.w),
                    pack_fp8x4(a1.x, a1.y, a1.z, a1.w)};
        *(uint2*)(x + (size_t)n * 256 + c8)       = ev;
        *(uint2*)(x + (size_t)n * 256 + 128 + c8) = av;
    } else if (t < N_NODES * 17) {
        int n = t - N_NODES * 16;
        float y0 = y[(size_t)n * 2 + 0];
        float y1 = y[(size_t)n * 2 + 1];
        out[n] = b1[0];
        out[N_NODES + n] = (float)(int)y1;
        out[2 * N_NODES + 2 * n + 0] = y0;
        out[2 * N_NODES + 2 * n + 1] = y1;
    } else {
        int e = t - N_NODES * 17;
        if (e < N_EDGES) atomicAdd(&deg[edge_index[N_EDGES + e]], 1);
    }
}

// ---------------------------------------------------------------------------
// CSR build: scan-free chunk allocation -> fill
// ---------------------------------------------------------------------------
__global__ __launch_bounds__(256) void k_alloc(
    const int* __restrict__ deg, int* __restrict__ off,
    int* __restrict__ cursor, int* __restrict__ total)
{
    int n = blockIdx.x * 256 + threadIdx.x;
    int lane = threadIdx.x & 63;
    int d = (n < N_NODES) ? deg[n] : 0;
    int incl = d;
    #pragma unroll
    for (int o = 1; o < 64; o <<= 1) {
        int v = __shfl_up(incl, o, 64);
        if (lane >= o) incl += v;
    }
    int wtot = __shfl(incl, 63, 64);
    int base = 0;
    if (lane == 63) base = atomicAdd(total, wtot);
    base = __shfl(base, 63, 64);
    if (n < N_NODES) {
        int o = base + incl - d;
        off[n] = o;
        cursor[n] = o;
    }
}

__global__ __launch_bounds__(256) void k_fill(
    const int* __restrict__ edge_index, int* __restrict__ cursor,
    int* __restrict__ slots)
{
    int e = blockIdx.x * 256 + threadIdx.x;
    if (e >= N_EDGES) return;
    int s = edge_index[e];
    int d = edge_index[N_EDGES + e];
    int slot = atomicAdd(&cursor[d], 1);
    slots[slot] = s;
}

// ---------------------------------------------------------------------------
// Gather-mean over fp8 rows (256B): 4 nodes/wave, 16 lanes x 16B, fp32 acc.
// ---------------------------------------------------------------------------
__global__ __launch_bounds__(256) void k_aggregate(
    const unsigned char* __restrict__ x,
    const int* __restrict__ off, const int* __restrict__ deg,
    const int* __restrict__ slots,
    unsigned char* __restrict__ agg)
{
    int g = blockIdx.x * 256 + threadIdx.x;
    int wid = g >> 6;
    int lane = g & 63;
    int sub = lane >> 4;
    int l16 = lane & 15;
    int n = wid * 4 + sub;
    bool active = n < N_NODES;
    int o = 0, d = 0;
    if (active) { o = off[n]; d = deg[n]; }
    float acc[16];
    #pragma unroll
    for (int i = 0; i < 16; ++i) acc[i] = 0.0f;
    for (int p = 0; p < d; ++p) {
        int src = slots[o + p];
        uint4 v = *(const uint4*)(x + (size_t)src * 256 + l16 * 16);
        unsigned int uu[4] = {v.x, v.y, v.z, v.w};
        #pragma unroll
        for (int j = 0; j < 4; ++j)
            #pragma unroll
            for (int b = 0; b < 4; ++b)
                acc[j * 4 + b] += fp82f((uu[j] >> (8 * b)) & 0xffu);
    }
    if (active) {
        float rs = 1.0f / fmaxf((float)d, 1.0f);
        uint4 ov;
        ov.x = pack_fp8x4(acc[0] * rs,  acc[1] * rs,  acc[2] * rs,  acc[3] * rs);
        ov.y = pack_fp8x4(acc[4] * rs,  acc[5] * rs,  acc[6] * rs,  acc[7] * rs);
        ov.z = pack_fp8x4(acc[8] * rs,  acc[9] * rs,  acc[10] * rs, acc[11] * rs);
        ov.w = pack_fp8x4(acc[12] * rs, acc[13] * rs, acc[14] * rs, acc[15] * rs);
        *(uint4*)(agg + (size_t)n * 256 + l16 * 16) = ov;
    }
}

// ---------------------------------------------------------------------------
// SAGE layer, fp8 MFMA, BK=128B (4 steps; was 8 at 64B -> barriers halved).
// 512 thr = 8 waves x 32 cols; tile 128x256; 3-buffer LDS (3x16KB).
// Staging: 2 issues x 16B/thread; LDS row = 128B (r gives NO bank bits),
// granule swizzle g' = g ^ ((r&3)<<1) (XOR on the h-bits) -> each fixed-h
// b64 read hits 16 bank-pairs x 4 lanes = the b64 inherent minimum.
// Step: vmcnt(2) -> barrier -> loadB(s+1) -> stage(s+2) -> 64 MFMA (4 h).
// Queue at top of s: [stage(s)x2, B(s)x8, stage(s+1)x2] -> vmcnt(2).
// Out = relu([Agg8|X8] @ Wt8^T + bias) -> fp8 (row 256B).
// ---------------------------------------------------------------------------
__global__ __launch_bounds__(512, 4) void k_sage(
    const unsigned char* __restrict__ Agg8,
    const unsigned char* __restrict__ X8,
    const unsigned char* __restrict__ Wt8,
    const float* __restrict__ bias,
    unsigned char* __restrict__ Out)
{
    __shared__ char smem[49152];    // 3 x (128 rows x 128B)

    const int tid  = threadIdx.x;
    const int w    = tid >> 6, lane = tid & 63;
    const int l15  = lane & 15, lg = lane >> 4;
    const int row0 = blockIdx.x * 128;

    f32x4 acc[8][2];
    #pragma unroll
    for (int i = 0; i < 8; ++i)
        #pragma unroll
        for (int n = 0; n < 2; ++n) acc[i][n] = (f32x4)0.0f;

    // staging: 8 thr/row x 16B granule; row = issue*64 + (tid>>3), g = tid&7
    const int srow = tid >> 3;      // 0..63
    const int sg   = tid & 7;

    auto stage = [&](int s) {
        const int b = s % 3;
        const unsigned char* base = (s < 2) ? Agg8 : X8;
        int k0 = (s & 1) * 128;
        #pragma unroll
        for (int issue = 0; issue < 2; ++issue) {
            int row  = srow + issue * 64;
            int grow = row0 + row;
            if (grow >= N_NODES) grow = N_NODES - 1;
            int gsrc = sg ^ ((row & 3) << 1);           // inverse swizzle
            const unsigned char* gp = base + (size_t)grow * 256 + k0 + gsrc * 16;
            const char* lp = smem + b * 16384 + issue * 8192 + tid * 16;
            __builtin_amdgcn_global_load_lds(
                (const __attribute__((address_space(1))) void*)gp,
                (__attribute__((address_space(3))) void*)lp, 16, 0, 0);
        }
    };

    auto loadB = [&](int s, i64v (&bb)[4][2]) {
        #pragma unroll
        for (int h = 0; h < 4; ++h)
            #pragma unroll
            for (int n = 0; n < 2; ++n) {
                int c = w * 32 + n * 16 + l15;
                bb[h][n] = *(const i64v*)(Wt8 + (size_t)c * 512 + s * 128
                                          + h * 32 + lg * 8);
            }
    };

    auto do_step = [&](int s, bool last, i64v (&bcur)[4][2], i64v (&bnxt)[4][2]) {
        const int b = s % 3;
        if (last) asm volatile("s_waitcnt vmcnt(0)" ::: "memory");
        else      asm volatile("s_waitcnt vmcnt(2)" ::: "memory");
        __builtin_amdgcn_sched_barrier(0);
        __builtin_amdgcn_s_barrier();
        __builtin_amdgcn_sched_barrier(0);
        if (!last) loadB(s + 1, bnxt);          // B prefetch for next step
        if (s + 2 < 4) stage(s + 2);            // 2-step-ahead A staging
        #pragma unroll
        for (int h = 0; h < 4; ++h) {
            const int g  = h * 2 + (lg >> 1);   // granule index (g[2:1]=h, g[0]=lg>>1)
            const int hf = lg & 1;
            #pragma unroll
            for (int i = 0; i < 8; ++i) {
                int r = i * 16 + l15;
                int gs = g ^ ((r & 3) << 1);    // swizzled granule
                i64v a = *(const i64v*)(smem + b * 16384 + r * 128
                                        + gs * 16 + hf * 8);
                acc[i][0] = __builtin_amdgcn_mfma_f32_16x16x32_fp8_fp8(
                    a, bcur[h][0], acc[i][0], 0, 0, 0);
                acc[i][1] = __builtin_amdgcn_mfma_f32_16x16x32_fp8_fp8(
                    a, bcur[h][1], acc[i][1], 0, 0, 0);
            }
        }
    };

    i64v b0[4][2], b1r[4][2];
    loadB(0, b0);       // queue: [B0 x8, st0 x2, st1 x2] -> vmcnt(2) at step 0 ok
    stage(0);
    stage(1);
    do_step(0, false, b0, b1r);
    do_step(1, false, b1r, b0);
    do_step(2, false, b0, b1r);
    do_step(3, true,  b1r, b0);

    __syncthreads();   // all waves done with staging before epilogue reuse
    unsigned char* lo = (unsigned char*)smem;     // 64x256 fp8 = 16KB half
    #pragma unroll
    for (int hh = 0; hh < 2; ++hh) {
        #pragma unroll
        for (int n = 0; n < 2; ++n) {
            int c = w * 32 + n * 16 + l15;
            float bv = bias[c];
            #pragma unroll
            for (int i2 = 0; i2 < 4; ++i2) {
                int i = hh * 4 + i2;
                #pragma unroll
                for (int r = 0; r < 4; ++r) {
                    int rl = i2 * 16 + lg * 4 + r;
                    lo[rl * 256 + c] = f2fp8(fmaxf(acc[i][n][r] + bv, 0.0f));
                }
            }
        }
        __syncthreads();
        #pragma unroll
        for (int q = 0; q < 2; ++q) {
            int chunk = tid + q * 512;      // 1024 x 16B = 64 rows x 256B
            int rl = chunk >> 4, cc = chunk & 15;
            int grow = row0 + hh * 64 + rl;
            if (grow < N_NODES)
                *(uint4*)(Out + (size_t)grow * 256 + cc * 16) =
                    *(const uint4*)((const char*)smem + rl * 256 + cc * 16);
        }
        __syncthreads();
    }
}

// ---------------------------------------------------------------------------
// HEAD, fp8, BK=128B (2 steps, 2 buffers):
// Pred += relu(X8 @ Wh8^T + b0) . W1  (Pred pre-init b1; atomicAdd partials)
// ---------------------------------------------------------------------------
__global__ __launch_bounds__(512, 4) void k_head8(
    const unsigned char* __restrict__ X8,
    const unsigned char* __restrict__ Wh8,
    const float* __restrict__ bias,
    const float* __restrict__ W1,
    float* __restrict__ Pred)
{
    __shared__ char smem[32768];    // 2 x 16KB

    const int tid  = threadIdx.x;
    const int w    = tid >> 6, lane = tid & 63;
    const int l15  = lane & 15, lg = lane >> 4;
    const int row0 = blockIdx.x * 128;

    f32x4 acc[8][2];
    #pragma unroll
    for (int i = 0; i < 8; ++i)
        #pragma unroll
        for (int n = 0; n < 2; ++n) acc[i][n] = (f32x4)0.0f;

    const int srow = tid >> 3;
    const int sg   = tid & 7;

    auto stage = [&](int s) {
        const int b = s & 1;
        #pragma unroll
        for (int issue = 0; issue < 2; ++issue) {
            int row  = srow + issue * 64;
            int grow = row0 + row;
            if (grow >= N_NODES) grow = N_NODES - 1;
            int gsrc = sg ^ ((row & 3) << 1);
            const unsigned char* gp = X8 + (size_t)grow * 256 + s * 128 + gsrc * 16;
            const char* lp = smem + b * 16384 + issue * 8192 + tid * 16;
            __builtin_amdgcn_global_load_lds(
                (const __attribute__((address_space(1))) void*)gp,
                (__attribute__((address_space(3))) void*)lp, 16, 0, 0);
        }
    };

    auto loadB = [&](int s, i64v (&bb)[4][2]) {
        #pragma unroll
        for (int h = 0; h < 4; ++h)
            #pragma unroll
            for (int n = 0; n < 2; ++n) {
                int c = w * 32 + n * 16 + l15;
                bb[h][n] = *(const i64v*)(Wh8 + (size_t)c * 256 + s * 128
                                          + h * 32 + lg * 8);
            }
    };

    auto do_step = [&](int s, bool last, i64v (&bcur)[4][2], i64v (&bnxt)[4][2]) {
        const int b = s & 1;
        if (last) asm volatile("s_waitcnt vmcnt(0)" ::: "memory");
        else      asm volatile("s_waitcnt vmcnt(2)" ::: "memory");
        __builtin_amdgcn_sched_barrier(0);
        __builtin_amdgcn_s_barrier();
        __builtin_amdgcn_sched_barrier(0);
        if (!last) loadB(s + 1, bnxt);
        #pragma unroll
        for (int h = 0; h < 4; ++h) {
            const int g  = h * 2 + (lg >> 1);
            const int hf = lg & 1;
            #pragma unroll
            for (int i = 0; i < 8; ++i) {
                int r = i * 16 + l15;
                int gs = g ^ ((r & 3) << 1);
                i64v a = *(const i64v*)(smem + b * 16384 + r * 128
                                        + gs * 16 + hf * 8);
                acc[i][0] = __builtin_amdgcn_mfma_f32_16x16x32_fp8_fp8(
                    a, bcur[h][0], acc[i][0], 0, 0, 0);
                acc[i][1] = __builtin_amdgcn_mfma_f32_16x16x32_fp8_fp8(
                    a, bcur[h][1], acc[i][1], 0, 0, 0);
            }
        }
    };

    i64v b0[4][2], b1r[4][2];
    loadB(0, b0);       // queue: [B0 x8, st0 x2, st1 x2] -> vmcnt(2) at step 0 ok
    stage(0);
    stage(1);
    do_step(0, false, b0, b1r);
    do_step(1, true,  b1r, b0);

    #pragma unroll
    for (int i = 0; i < 8; ++i) {
        float p[4];
        #pragma unroll
        for (int r = 0; r < 4; ++r) p[r] = 0.0f;
        #pragma unroll
        for (int n = 0; n < 2; ++n) {
            int cg = w * 32 + n * 16 + l15;
            float bv = bias[cg];
            float wv = W1[cg];
            #pragma unroll
            for (int r = 0; r < 4; ++r)
                p[r] += fmaxf(acc[i][n][r] + bv, 0.0f) * wv;
        }
        #pragma unroll
        for (int r = 0; r < 4; ++r) {
            float s = p[r];
            #pragma unroll
            for (int m = 1; m < 16; m <<= 1) s += __shfl_xor(s, m, 64);
            if (l15 == 0) {
                int row = row0 + i * 16 + lg * 4 + r;
                if (row < N_NODES) atomicAdd(&Pred[row], s);
            }
        }
    }
}

extern "C" void kernel_launch(void* const* d_in, const int* in_sizes, int n_in,
                              void* d_out, int out_size, void* d_ws, size_t ws_size,
                              hipStream_t stream) {
    const float* node_attr = (const float*)d_in[0];
    const float* y         = (const float*)d_in[1];
    const float* node_emb  = (const float*)d_in[2];
    const float* net_W     = (const float*)d_in[4];
    const float* net_b     = (const float*)d_in[5];
    const float* dev_W     = (const float*)d_in[6];
    const float* dev_b     = (const float*)d_in[7];
    const float* pin_emb   = (const float*)d_in[8];
    const float* sage_Wl   = (const float*)d_in[9];
    const float* sage_bl   = (const float*)d_in[10];
    const float* sage_Wr   = (const float*)d_in[11];
    const float* head_W0   = (const float*)d_in[12];
    const float* head_b0   = (const float*)d_in[13];
    const float* head_W1   = (const float*)d_in[14];
    const float* head_b1   = (const float*)d_in[15];
    const int*   node_type = (const int*)d_in[16];
    const int*   edge_idx  = (const int*)d_in[18];
    float* out = (float*)d_out;

    const size_t x8b = (size_t)N_NODES * 256;       // fp8 row bytes
    char* p = (char*)d_ws;
    unsigned char* x0   = (unsigned char*)p;  p += x8b;
    unsigned char* x1   = (unsigned char*)p;  p += x8b;
    unsigned char* agg8 = (unsigned char*)p;  p += x8b;
    unsigned char* Wt8  = (unsigned char*)p;  p += (size_t)3 * 256 * 512;
    unsigned char* Wh8  = (unsigned char*)p;  p += (size_t)256 * 256;
    int* deg    = (int*)p; p += N_NODES * 4;
    int* off    = (int*)p; p += N_NODES * 4;
    int* cursor = (int*)p; p += N_NODES * 4;
    int* slots  = (int*)p; p += N_EDGES * 4;
    int* total  = (int*)p; p += 16;

    k_prep<<<(3 * 131072 + 65536 + 255) / 256, 256, 0, stream>>>(
        sage_Wl, sage_Wr, head_W0, Wt8, Wh8, deg, total);
    k_init<<<(N_NODES * 17 + N_EDGES + 255) / 256, 256, 0, stream>>>(
        node_attr, node_emb, net_W, net_b, dev_W, dev_b, pin_emb, node_type,
        y, head_b1, edge_idx, deg, out, x0);
    k_alloc<<<(N_NODES + 255) / 256, 256, 0, stream>>>(deg, off, cursor, total);
    k_fill<<<(N_EDGES + 255) / 256, 256, 0, stream>>>(edge_idx, cursor, slots);

    const int agg_grid  = (N_NODES / 4 * 64 + 255) / 256;
    const int gemm_grid = (N_NODES + 127) / 128;
    // layer 1
    k_aggregate<<<agg_grid, 256, 0, stream>>>(x0, off, deg, slots, agg8);
    k_sage<<<gemm_grid, 512, 0, stream>>>(agg8, x0, Wt8, sage_bl, x1);
    // layer 2
    k_aggregate<<<agg_grid, 256, 0, stream>>>(x1, off, deg, slots, agg8);
    k_sage<<<gemm_grid, 512, 0, stream>>>(agg8, x1, Wt8 + 131072,
                                          sage_bl + HID, x0);
    // layer 3
    k_aggregate<<<agg_grid, 256, 0, stream>>>(x0, off, deg, slots, agg8);
    k_sage<<<gemm_grid, 512, 0, stream>>>(agg8, x0, Wt8 + 262144,
                                          sage_bl + 2 * HID, x1);
    // head
    k_head8<<<gemm_grid, 512, 0, stream>>>(x1, Wh8, head_b0, head_W1, out);
}

// Round 18
// 337.922 us; speedup vs baseline: 1.0265x; 1.0265x over previous
//
#include <hip/hip_runtime.h>
#include <hip/hip_bf16.h>
#include <hip/hip_fp8.h>

#define N_NODES 100000
#define N_EDGES 320000
#define HID 256
#define NE 128

typedef __attribute__((ext_vector_type(4))) float f32x4;
typedef long long i64v;

__device__ inline unsigned char f2fp8(float f) { return __hip_fp8_e4m3(f).__x; }
__device__ inline float fp82f(unsigned char b) {
    __hip_fp8_e4m3 h; h.__x = b; return (float)h;
}
__device__ inline unsigned int pack_fp8x4(float a, float b, float c, float d) {
    return (unsigned)f2fp8(a) | ((unsigned)f2fp8(b) << 8) |
           ((unsigned)f2fp8(c) << 16) | ((unsigned)f2fp8(d) << 24);
}

// ---------------------------------------------------------------------------
// Weight prep: sage + head weights fp32 -> fp8 [n][k].  Zeroes deg/total.
// ---------------------------------------------------------------------------
__global__ __launch_bounds__(256) void k_prep(
    const float* __restrict__ Wl, const float* __restrict__ Wr,
    const float* __restrict__ W0,
    unsigned char* __restrict__ Wt8, unsigned char* __restrict__ Wh8,
    int* __restrict__ deg, int* __restrict__ total)
{
    int t = blockIdx.x * 256 + threadIdx.x;
    const int total_sage = 3 * 256 * 512;
    if (t < total_sage) {
        int l = t >> 17;
        int rem = t & 131071;
        int n = rem >> 9;
        int k = rem & 511;
        const float* Wsrc = (k < 256) ? (Wl + (size_t)l * 65536)
                                      : (Wr + (size_t)l * 65536);
        Wt8[t] = f2fp8(Wsrc[(k & 255) * 256 + n]);
    } else {
        int u = t - total_sage;
        if (u < 65536) {
            int n = u >> 8, k = u & 255;
            Wh8[u] = f2fp8(W0[k * 256 + n]);
        }
    }
    if (t < N_NODES) deg[t] = 0;
    if (t == 0) *total = 0;
}

// ---------------------------------------------------------------------------
// Init: x0 in fp8 (row = 256B: [emb 0..127 | attr 128..255]).
// 16 thr/node x 8 cols, uint2 stores.  Tail ranges: output tail + histogram.
// ---------------------------------------------------------------------------
__global__ __launch_bounds__(256) void k_init(
    const float* __restrict__ node_attr,
    const float* __restrict__ node_emb,
    const float* __restrict__ net_W, const float* __restrict__ net_b,
    const float* __restrict__ dev_W, const float* __restrict__ dev_b,
    const float* __restrict__ pin_emb,
    const int*   __restrict__ node_type,
    const float* __restrict__ y, const float* __restrict__ b1,
    const int*   __restrict__ edge_index, int* __restrict__ deg,
    float* __restrict__ out,
    unsigned char* __restrict__ x)
{
    int t = blockIdx.x * 256 + threadIdx.x;
    if (t < N_NODES * 16) {
        int n  = t >> 4;
        int c8 = (t & 15) * 8;
        int ty = node_type[n];
        float4 e0 = *(const float4*)(node_emb + ty * NE + c8);
        float4 e1 = *(const float4*)(node_emb + ty * NE + c8 + 4);
        float4 a0, a1;
        if (ty == 0 || ty == 1) {
            const float* W = (ty == 0) ? net_W : dev_W;
            const float* b = (ty == 0) ? net_b : dev_b;
            a0 = *(const float4*)(b + c8);
            a1 = *(const float4*)(b + c8 + 4);
            const float* ar = node_attr + (size_t)n * 17;
            #pragma unroll
            for (int k = 0; k < 17; ++k) {
                float av = ar[k];
                float4 w0 = *(const float4*)(W + k * NE + c8);
                float4 w1 = *(const float4*)(W + k * NE + c8 + 4);
                a0.x += av * w0.x; a0.y += av * w0.y;
                a0.z += av * w0.z; a0.w += av * w0.w;
                a1.x += av * w1.x; a1.y += av * w1.y;
                a1.z += av * w1.z; a1.w += av * w1.w;
            }
        } else if (ty == 2) {
            int idx = (int)node_attr[(size_t)n * 17];
            a0 = *(const float4*)(pin_emb + idx * NE + c8);
            a1 = *(const float4*)(pin_emb + idx * NE + c8 + 4);
        } else {
            a0.x = a0.y = a0.z = a0.w = 0.0f;
            a1 = a0;
        }
        uint2 ev = {pack_fp8x4(e0.x, e0.y, e0.z, e0.w),
                    pack_fp8x4(e1.x, e1.y, e1.z, e1.w)};
        uint2 av = {pack_fp8x4(a0.x, a0.y, a0.z, a0.w),
                    pack_fp8x4(a1.x, a1.y, a1.z, a1.w)};
        *(uint2*)(x + (size_t)n * 256 + c8)       = ev;
        *(uint2*)(x + (size_t)n * 256 + 128 + c8) = av;
    } else if (t < N_NODES * 17) {
        int n = t - N_NODES * 16;
        float y0 = y[(size_t)n * 2 + 0];
        float y1 = y[(size_t)n * 2 + 1];
        out[n] = b1[0];
        out[N_NODES + n] = (float)(int)y1;
        out[2 * N_NODES + 2 * n + 0] = y0;
        out[2 * N_NODES + 2 * n + 1] = y1;
    } else {
        int e = t - N_NODES * 17;
        if (e < N_EDGES) atomicAdd(&deg[edge_index[N_EDGES + e]], 1);
    }
}

// ---------------------------------------------------------------------------
// CSR build: scan-free chunk allocation -> fill
// ---------------------------------------------------------------------------
__global__ __launch_bounds__(256) void k_alloc(
    const int* __restrict__ deg, int* __restrict__ off,
    int* __restrict__ cursor, int* __restrict__ total)
{
    int n = blockIdx.x * 256 + threadIdx.x;
    int lane = threadIdx.x & 63;
    int d = (n < N_NODES) ? deg[n] : 0;
    int incl = d;
    #pragma unroll
    for (int o = 1; o < 64; o <<= 1) {
        int v = __shfl_up(incl, o, 64);
        if (lane >= o) incl += v;
    }
    int wtot = __shfl(incl, 63, 64);
    int base = 0;
    if (lane == 63) base = atomicAdd(total, wtot);
    base = __shfl(base, 63, 64);
    if (n < N_NODES) {
        int o = base + incl - d;
        off[n] = o;
        cursor[n] = o;
    }
}

__global__ __launch_bounds__(256) void k_fill(
    const int* __restrict__ edge_index, int* __restrict__ cursor,
    int* __restrict__ slots)
{
    int e = blockIdx.x * 256 + threadIdx.x;
    if (e >= N_EDGES) return;
    int s = edge_index[e];
    int d = edge_index[N_EDGES + e];
    int slot = atomicAdd(&cursor[d], 1);
    slots[slot] = s;
}

// ---------------------------------------------------------------------------
// Gather-mean over fp8 rows (256B): 4 nodes/wave, 16 lanes x 16B, fp32 acc.
// ---------------------------------------------------------------------------
__global__ __launch_bounds__(256) void k_aggregate(
    const unsigned char* __restrict__ x,
    const int* __restrict__ off, const int* __restrict__ deg,
    const int* __restrict__ slots,
    unsigned char* __restrict__ agg)
{
    int g = blockIdx.x * 256 + threadIdx.x;
    int wid = g >> 6;
    int lane = g & 63;
    int sub = lane >> 4;
    int l16 = lane & 15;
    int n = wid * 4 + sub;
    bool active = n < N_NODES;
    int o = 0, d = 0;
    if (active) { o = off[n]; d = deg[n]; }
    float acc[16];
    #pragma unroll
    for (int i = 0; i < 16; ++i) acc[i] = 0.0f;
    for (int p = 0; p < d; ++p) {
        int src = slots[o + p];
        uint4 v = *(const uint4*)(x + (size_t)src * 256 + l16 * 16);
        unsigned int uu[4] = {v.x, v.y, v.z, v.w};
        #pragma unroll
        for (int j = 0; j < 4; ++j)
            #pragma unroll
            for (int b = 0; b < 4; ++b)
                acc[j * 4 + b] += fp82f((uu[j] >> (8 * b)) & 0xffu);
    }
    if (active) {
        float rs = 1.0f / fmaxf((float)d, 1.0f);
        uint4 ov;
        ov.x = pack_fp8x4(acc[0] * rs,  acc[1] * rs,  acc[2] * rs,  acc[3] * rs);
        ov.y = pack_fp8x4(acc[4] * rs,  acc[5] * rs,  acc[6] * rs,  acc[7] * rs);
        ov.z = pack_fp8x4(acc[8] * rs,  acc[9] * rs,  acc[10] * rs, acc[11] * rs);
        ov.w = pack_fp8x4(acc[12] * rs, acc[13] * rs, acc[14] * rs, acc[15] * rs);
        *(uint4*)(agg + (size_t)n * 256 + l16 * 16) = ov;
    }
}

// ---------------------------------------------------------------------------
// SAGE layer, fp8 MFMA (R10 skeleton).  Swizzle key (r>>1)&3: drawn from
// bits disjoint with the bank-row bit r&1 -> 16 distinct bank-pairs per
// 64-lane ds_read_b64 = the b64 inherent minimum (~4M residual conflicts).
// 512 thr = 8 waves x 32 cols; tile 128x256, BK=64B; 3-buffer LDS,
// single barrier/step, steady vmcnt(1) ([stage(s), B(s)x4, stage(s+1)]).
// Out = relu([Agg8|X8] @ Wt8^T + bias) -> fp8 (row 256B).
// ---------------------------------------------------------------------------
__global__ __launch_bounds__(512, 4) void k_sage(
    const unsigned char* __restrict__ Agg8,
    const unsigned char* __restrict__ X8,
    const unsigned char* __restrict__ Wt8,
    const float* __restrict__ bias,
    unsigned char* __restrict__ Out)
{
    __shared__ char smem[32768];    // staging 3x8KB; epilogue tile reuse

    const int tid  = threadIdx.x;
    const int w    = tid >> 6, lane = tid & 63;
    const int l15  = lane & 15, lg = lane >> 4;
    const int row0 = blockIdx.x * 128;

    f32x4 acc[8][2];
    #pragma unroll
    for (int i = 0; i < 8; ++i)
        #pragma unroll
        for (int n = 0; n < 2; ++n) acc[i][n] = (f32x4)0.0f;

    // staging: 4 thr/row x 16B; row = tid>>2 (0..127), c16 = tid&3
    const int srow = tid >> 2;
    const int c16s = tid & 3;
    int sgrow = row0 + srow; if (sgrow >= N_NODES) sgrow = N_NODES - 1;
    const int skey = (srow >> 1) & 3;

    auto stage = [&](int s) {
        const int b = s % 3;
        const unsigned char* base = (s < 4) ? Agg8 : X8;
        int k0 = (s & 3) * 64;
        const unsigned char* gp = base + (size_t)sgrow * 256 + k0
                                + ((c16s ^ skey) << 4);         // inverse swizzle
        const char* lp = smem + b * 8192 + tid * 16;            // linear dest
        __builtin_amdgcn_global_load_lds(
            (const __attribute__((address_space(1))) void*)gp,
            (__attribute__((address_space(3))) void*)lp, 16, 0, 0);
    };

    auto loadB = [&](int s, i64v (&bb)[2][2]) {
        #pragma unroll
        for (int h = 0; h < 2; ++h)
            #pragma unroll
            for (int n = 0; n < 2; ++n) {
                int c = w * 32 + n * 16 + l15;
                bb[h][n] = *(const i64v*)(Wt8 + (size_t)c * 512 + s * 64
                                          + h * 32 + lg * 8);
            }
    };

    auto do_step = [&](int s, bool last, i64v (&bcur)[2][2], i64v (&bnxt)[2][2]) {
        const int b = s % 3;
        if (last) asm volatile("s_waitcnt vmcnt(0)" ::: "memory");
        else      asm volatile("s_waitcnt vmcnt(1)" ::: "memory");
        __builtin_amdgcn_sched_barrier(0);
        __builtin_amdgcn_s_barrier();
        __builtin_amdgcn_sched_barrier(0);
        if (!last) loadB(s + 1, bnxt);          // B prefetch for next step
        if (s + 2 < 8) stage(s + 2);            // 2-step-ahead A staging
        #pragma unroll
        for (int h = 0; h < 2; ++h) {
            const int c8 = h * 4 + lg;          // 8B chunk index 0..7
            #pragma unroll
            for (int i = 0; i < 8; ++i) {
                int r = i * 16 + l15;
                i64v a = *(const i64v*)(smem + b * 8192 + r * 64
                            + ((((c8 >> 1) ^ ((r >> 1) & 3)) << 4)
                               | ((c8 & 1) << 3)));
                acc[i][0] = __builtin_amdgcn_mfma_f32_16x16x32_fp8_fp8(
                    a, bcur[h][0], acc[i][0], 0, 0, 0);
                acc[i][1] = __builtin_amdgcn_mfma_f32_16x16x32_fp8_fp8(
                    a, bcur[h][1], acc[i][1], 0, 0, 0);
            }
        }
    };

    i64v b0[2][2], b1r[2][2];
    loadB(0, b0);       // queue: [B0 x4, st0, st1] -> vmcnt(1) at step 0 ok
    stage(0);
    stage(1);
    do_step(0, false, b0, b1r);
    do_step(1, false, b1r, b0);
    do_step(2, false, b0, b1r);
    do_step(3, false, b1r, b0);
    do_step(4, false, b0, b1r);
    do_step(5, false, b1r, b0);
    do_step(6, false, b0, b1r);
    do_step(7, true,  b1r, b0);

    __syncthreads();   // all waves done with staging before epilogue reuse
    unsigned char* lo = (unsigned char*)smem;     // 64x256 fp8 = 16KB half
    #pragma unroll
    for (int hh = 0; hh < 2; ++hh) {
        #pragma unroll
        for (int n = 0; n < 2; ++n) {
            int c = w * 32 + n * 16 + l15;
            float bv = bias[c];
            #pragma unroll
            for (int i2 = 0; i2 < 4; ++i2) {
                int i = hh * 4 + i2;
                #pragma unroll
                for (int r = 0; r < 4; ++r) {
                    int rl = i2 * 16 + lg * 4 + r;
                    lo[rl * 256 + c] = f2fp8(fmaxf(acc[i][n][r] + bv, 0.0f));
                }
            }
        }
        __syncthreads();
        #pragma unroll
        for (int q = 0; q < 2; ++q) {
            int chunk = tid + q * 512;      // 1024 x 16B = 64 rows x 256B
            int rl = chunk >> 4, cc = chunk & 15;
            int grow = row0 + hh * 64 + rl;
            if (grow < N_NODES)
                *(uint4*)(Out + (size_t)grow * 256 + cc * 16) =
                    *(const uint4*)((const char*)smem + rl * 256 + cc * 16);
        }
        __syncthreads();
    }
}

// ---------------------------------------------------------------------------
// HEAD, fp8: Pred += relu(X8 @ Wh8^T + b0) . W1  (K=256, 4 steps; same
// staging/swizzle as k_sage; Pred pre-init b1; atomicAdd partials).
// ---------------------------------------------------------------------------
__global__ __launch_bounds__(512, 4) void k_head8(
    const unsigned char* __restrict__ X8,
    const unsigned char* __restrict__ Wh8,
    const float* __restrict__ bias,
    const float* __restrict__ W1,
    float* __restrict__ Pred)
{
    __shared__ char smem[24576];    // 3x8KB staging

    const int tid  = threadIdx.x;
    const int w    = tid >> 6, lane = tid & 63;
    const int l15  = lane & 15, lg = lane >> 4;
    const int row0 = blockIdx.x * 128;

    f32x4 acc[8][2];
    #pragma unroll
    for (int i = 0; i < 8; ++i)
        #pragma unroll
        for (int n = 0; n < 2; ++n) acc[i][n] = (f32x4)0.0f;

    const int srow = tid >> 2;
    const int c16s = tid & 3;
    int sgrow = row0 + srow; if (sgrow >= N_NODES) sgrow = N_NODES - 1;
    const int skey = (srow >> 1) & 3;

    auto stage = [&](int s) {
        const int b = s % 3;
        const unsigned char* gp = X8 + (size_t)sgrow * 256 + s * 64
                                + ((c16s ^ skey) << 4);
        const char* lp = smem + b * 8192 + tid * 16;
        __builtin_amdgcn_global_load_lds(
            (const __attribute__((address_space(1))) void*)gp,
            (__attribute__((address_space(3))) void*)lp, 16, 0, 0);
    };

    auto loadB = [&](int s, i64v (&bb)[2][2]) {
        #pragma unroll
        for (int h = 0; h < 2; ++h)
            #pragma unroll
            for (int n = 0; n < 2; ++n) {
                int c = w * 32 + n * 16 + l15;
                bb[h][n] = *(const i64v*)(Wh8 + (size_t)c * 256 + s * 64
                                          + h * 32 + lg * 8);
            }
    };

    auto do_step = [&](int s, bool last, i64v (&bcur)[2][2], i64v (&bnxt)[2][2]) {
        const int b = s % 3;
        if (last) asm volatile("s_waitcnt vmcnt(0)" ::: "memory");
        else      asm volatile("s_waitcnt vmcnt(1)" ::: "memory");
        __builtin_amdgcn_sched_barrier(0);
        __builtin_amdgcn_s_barrier();
        __builtin_amdgcn_sched_barrier(0);
        if (!last) loadB(s + 1, bnxt);
        if (s + 2 < 4) stage(s + 2);
        #pragma unroll
        for (int h = 0; h < 2; ++h) {
            const int c8 = h * 4 + lg;
            #pragma unroll
            for (int i = 0; i < 8; ++i) {
                int r = i * 16 + l15;
                i64v a = *(const i64v*)(smem + b * 8192 + r * 64
                            + ((((c8 >> 1) ^ ((r >> 1) & 3)) << 4)
                               | ((c8 & 1) << 3)));
                acc[i][0] = __builtin_amdgcn_mfma_f32_16x16x32_fp8_fp8(
                    a, bcur[h][0], acc[i][0], 0, 0, 0);
                acc[i][1] = __builtin_amdgcn_mfma_f32_16x16x32_fp8_fp8(
                    a, bcur[h][1], acc[i][1], 0, 0, 0);
            }
        }
    };

    i64v b0[2][2], b1r[2][2];
    loadB(0, b0);
    stage(0);
    stage(1);
    do_step(0, false, b0, b1r);
    do_step(1, false, b1r, b0);
    do_step(2, false, b0, b1r);
    do_step(3, true,  b1r, b0);

    #pragma unroll
    for (int i = 0; i < 8; ++i) {
        float p[4];
        #pragma unroll
        for (int r = 0; r < 4; ++r) p[r] = 0.0f;
        #pragma unroll
        for (int n = 0; n < 2; ++n) {
            int cg = w * 32 + n * 16 + l15;
            float bv = bias[cg];
            float wv = W1[cg];
            #pragma unroll
            for (int r = 0; r < 4; ++r)
                p[r] += fmaxf(acc[i][n][r] + bv, 0.0f) * wv;
        }
        #pragma unroll
        for (int r = 0; r < 4; ++r) {
            float s = p[r];
            #pragma unroll
            for (int m = 1; m < 16; m <<= 1) s += __shfl_xor(s, m, 64);
            if (l15 == 0) {
                int row = row0 + i * 16 + lg * 4 + r;
                if (row < N_NODES) atomicAdd(&Pred[row], s);
            }
        }
    }
}

extern "C" void kernel_launch(void* const* d_in, const int* in_sizes, int n_in,
                              void* d_out, int out_size, void* d_ws, size_t ws_size,
                              hipStream_t stream) {
    const float* node_attr = (const float*)d_in[0];
    const float* y         = (const float*)d_in[1];
    const float* node_emb  = (const float*)d_in[2];
    const float* net_W     = (const float*)d_in[4];
    const float* net_b     = (const float*)d_in[5];
    const float* dev_W     = (const float*)d_in[6];
    const float* dev_b     = (const float*)d_in[7];
    const float* pin_emb   = (const float*)d_in[8];
    const float* sage_Wl   = (const float*)d_in[9];
    const float* sage_bl   = (const float*)d_in[10];
    const float* sage_Wr   = (const float*)d_in[11];
    const float* head_W0   = (const float*)d_in[12];
    const float* head_b0   = (const float*)d_in[13];
    const float* head_W1   = (const float*)d_in[14];
    const float* head_b1   = (const float*)d_in[15];
    const int*   node_type = (const int*)d_in[16];
    const int*   edge_idx  = (const int*)d_in[18];
    float* out = (float*)d_out;

    const size_t x8b = (size_t)N_NODES * 256;       // fp8 row bytes
    char* p = (char*)d_ws;
    unsigned char* x0   = (unsigned char*)p;  p += x8b;
    unsigned char* x1   = (unsigned char*)p;  p += x8b;
    unsigned char* agg8 = (unsigned char*)p;  p += x8b;
    unsigned char* Wt8  = (unsigned char*)p;  p += (size_t)3 * 256 * 512;
    unsigned char* Wh8  = (unsigned char*)p;  p += (size_t)256 * 256;
    int* deg    = (int*)p; p += N_NODES * 4;
    int* off    = (int*)p; p += N_NODES * 4;
    int* cursor = (int*)p; p += N_NODES * 4;
    int* slots  = (int*)p; p += N_EDGES * 4;
    int* total  = (int*)p; p += 16;

    k_prep<<<(3 * 131072 + 65536 + 255) / 256, 256, 0, stream>>>(
        sage_Wl, sage_Wr, head_W0, Wt8, Wh8, deg, total);
    k_init<<<(N_NODES * 17 + N_EDGES + 255) / 256, 256, 0, stream>>>(
        node_attr, node_emb, net_W, net_b, dev_W, dev_b, pin_emb, node_type,
        y, head_b1, edge_idx, deg, out, x0);
    k_alloc<<<(N_NODES + 255) / 256, 256, 0, stream>>>(deg, off, cursor, total);
    k_fill<<<(N_EDGES + 255) / 256, 256, 0, stream>>>(edge_idx, cursor, slots);

    const int agg_grid  = (N_NODES / 4 * 64 + 255) / 256;
    const int gemm_grid = (N_NODES + 127) / 128;
    // layer 1
    k_aggregate<<<agg_grid, 256, 0, stream>>>(x0, off, deg, slots, agg8);
    k_sage<<<gemm_grid, 512, 0, stream>>>(agg8, x0, Wt8, sage_bl, x1);
    // layer 2
    k_aggregate<<<agg_grid, 256, 0, stream>>>(x1, off, deg, slots, agg8);
    k_sage<<<gemm_grid, 512, 0, stream>>>(agg8, x1, Wt8 + 131072,
                                          sage_bl + HID, x0);
    // layer 3
    k_aggregate<<<agg_grid, 256, 0, stream>>>(x0, off, deg, slots, agg8);
    k_sage<<<gemm_grid, 512, 0, stream>>>(agg8, x0, Wt8 + 262144,
                                          sage_bl + 2 * HID, x1);
    // head
    k_head8<<<gemm_grid, 512, 0, stream>>>(x1, Wh8, head_b0, head_W1, out);
}

// Round 19
// 331.745 us; speedup vs baseline: 1.0456x; 1.0186x over previous
//
#include <hip/hip_runtime.h>
#include <hip/hip_bf16.h>
#include <hip/hip_fp8.h>

#define N_NODES 100000
#define N_EDGES 320000
#define HID 256
#define NE 128

typedef __attribute__((ext_vector_type(4))) float f32x4;
typedef long long i64v;

__device__ inline unsigned char f2fp8(float f) { return __hip_fp8_e4m3(f).__x; }
__device__ inline float fp82f(unsigned char b) {
    __hip_fp8_e4m3 h; h.__x = b; return (float)h;
}
__device__ inline unsigned int pack_fp8x4(float a, float b, float c, float d) {
    return (unsigned)f2fp8(a) | ((unsigned)f2fp8(b) << 8) |
           ((unsigned)f2fp8(c) << 16) | ((unsigned)f2fp8(d) << 24);
}

// ---------------------------------------------------------------------------
// Weight prep: sage + head weights fp32 -> fp8 [n][k].  Zeroes deg/total.
// ---------------------------------------------------------------------------
__global__ __launch_bounds__(256) void k_prep(
    const float* __restrict__ Wl, const float* __restrict__ Wr,
    const float* __restrict__ W0,
    unsigned char* __restrict__ Wt8, unsigned char* __restrict__ Wh8,
    int* __restrict__ deg, int* __restrict__ total)
{
    int t = blockIdx.x * 256 + threadIdx.x;
    const int total_sage = 3 * 256 * 512;
    if (t < total_sage) {
        int l = t >> 17;
        int rem = t & 131071;
        int n = rem >> 9;
        int k = rem & 511;
        const float* Wsrc = (k < 256) ? (Wl + (size_t)l * 65536)
                                      : (Wr + (size_t)l * 65536);
        Wt8[t] = f2fp8(Wsrc[(k & 255) * 256 + n]);
    } else {
        int u = t - total_sage;
        if (u < 65536) {
            int n = u >> 8, k = u & 255;
            Wh8[u] = f2fp8(W0[k * 256 + n]);
        }
    }
    if (t < N_NODES) deg[t] = 0;
    if (t == 0) *total = 0;
}

// ---------------------------------------------------------------------------
// Init: x0 in fp8 (row = 256B: [emb 0..127 | attr 128..255]).
// All weights staged in LDS (27.5KB); divergence-free 17-FMA loop (ty 2/3
// lanes compute a discarded dummy against net_W; overrides applied after).
// 16 thr/node x 8 cols, uint2 stores.  Tail ranges: output tail + histogram.
// ---------------------------------------------------------------------------
__global__ __launch_bounds__(256) void k_init(
    const float* __restrict__ node_attr,
    const float* __restrict__ node_emb,
    const float* __restrict__ net_W, const float* __restrict__ net_b,
    const float* __restrict__ dev_W, const float* __restrict__ dev_b,
    const float* __restrict__ pin_emb,
    const int*   __restrict__ node_type,
    const float* __restrict__ y, const float* __restrict__ b1,
    const int*   __restrict__ edge_index, int* __restrict__ deg,
    float* __restrict__ out,
    unsigned char* __restrict__ x)
{
    // LDS: net_W[17x128] | dev_W[17x128] | pin_emb[17x128] | node_emb[4x128]
    __shared__ float lds[7040];     // 28160 B
    {
        float4* d = (float4*)lds;
        for (int i = threadIdx.x; i < 544; i += 256)
            d[i] = ((const float4*)net_W)[i];
        for (int i = threadIdx.x; i < 544; i += 256)
            d[544 + i] = ((const float4*)dev_W)[i];
        for (int i = threadIdx.x; i < 544; i += 256)
            d[1088 + i] = ((const float4*)pin_emb)[i];
        for (int i = threadIdx.x; i < 128; i += 256)
            d[1632 + i] = ((const float4*)node_emb)[i];
    }
    __syncthreads();

    int t = blockIdx.x * 256 + threadIdx.x;
    if (t < N_NODES * 16) {
        int n  = t >> 4;
        int c8 = (t & 15) * 8;
        int c4 = c8 >> 2;
        int ty = node_type[n];
        const float4* ldsv = (const float4*)lds;

        float4 e0 = ldsv[1632 + ty * 32 + c4];
        float4 e1 = ldsv[1632 + ty * 32 + c4 + 1];

        const float* ar = node_attr + (size_t)n * 17;
        const float* bb = (ty == 1) ? dev_b : net_b;
        float4 a0 = *(const float4*)(bb + c8);
        float4 a1 = *(const float4*)(bb + c8 + 4);
        const int wb4 = (ty == 1) ? 544 : 0;    // float4 base of W in LDS
        #pragma unroll
        for (int k = 0; k < 17; ++k) {
            float av = ar[k];
            float4 w0 = ldsv[wb4 + k * 32 + c4];
            float4 w1 = ldsv[wb4 + k * 32 + c4 + 1];
            a0.x += av * w0.x; a0.y += av * w0.y;
            a0.z += av * w0.z; a0.w += av * w0.w;
            a1.x += av * w1.x; a1.y += av * w1.y;
            a1.z += av * w1.z; a1.w += av * w1.w;
        }
        if (ty == 2) {
            int idx = (int)ar[0];
            a0 = ldsv[1088 + idx * 32 + c4];
            a1 = ldsv[1088 + idx * 32 + c4 + 1];
        } else if (ty == 3) {
            a0.x = a0.y = a0.z = a0.w = 0.0f;
            a1 = a0;
        }

        uint2 ev = {pack_fp8x4(e0.x, e0.y, e0.z, e0.w),
                    pack_fp8x4(e1.x, e1.y, e1.z, e1.w)};
        uint2 av = {pack_fp8x4(a0.x, a0.y, a0.z, a0.w),
                    pack_fp8x4(a1.x, a1.y, a1.z, a1.w)};
        *(uint2*)(x + (size_t)n * 256 + c8)       = ev;
        *(uint2*)(x + (size_t)n * 256 + 128 + c8) = av;
    } else if (t < N_NODES * 17) {
        int n = t - N_NODES * 16;
        float y0 = y[(size_t)n * 2 + 0];
        float y1 = y[(size_t)n * 2 + 1];
        out[n] = b1[0];
        out[N_NODES + n] = (float)(int)y1;
        out[2 * N_NODES + 2 * n + 0] = y0;
        out[2 * N_NODES + 2 * n + 1] = y1;
    } else {
        int e = t - N_NODES * 17;
        if (e < N_EDGES) atomicAdd(&deg[edge_index[N_EDGES + e]], 1);
    }
}

// ---------------------------------------------------------------------------
// CSR build: scan-free chunk allocation -> fill
// ---------------------------------------------------------------------------
__global__ __launch_bounds__(256) void k_alloc(
    const int* __restrict__ deg, int* __restrict__ off,
    int* __restrict__ cursor, int* __restrict__ total)
{
    int n = blockIdx.x * 256 + threadIdx.x;
    int lane = threadIdx.x & 63;
    int d = (n < N_NODES) ? deg[n] : 0;
    int incl = d;
    #pragma unroll
    for (int o = 1; o < 64; o <<= 1) {
        int v = __shfl_up(incl, o, 64);
        if (lane >= o) incl += v;
    }
    int wtot = __shfl(incl, 63, 64);
    int base = 0;
    if (lane == 63) base = atomicAdd(total, wtot);
    base = __shfl(base, 63, 64);
    if (n < N_NODES) {
        int o = base + incl - d;
        off[n] = o;
        cursor[n] = o;
    }
}

__global__ __launch_bounds__(256) void k_fill(
    const int* __restrict__ edge_index, int* __restrict__ cursor,
    int* __restrict__ slots)
{
    int e = blockIdx.x * 256 + threadIdx.x;
    if (e >= N_EDGES) return;
    int s = edge_index[e];
    int d = edge_index[N_EDGES + e];
    int slot = atomicAdd(&cursor[d], 1);
    slots[slot] = s;
}

// ---------------------------------------------------------------------------
// Gather-mean over fp8 rows (256B): 4 nodes/wave, 16 lanes x 16B, fp32 acc.
// ---------------------------------------------------------------------------
__global__ __launch_bounds__(256) void k_aggregate(
    const unsigned char* __restrict__ x,
    const int* __restrict__ off, const int* __restrict__ deg,
    const int* __restrict__ slots,
    unsigned char* __restrict__ agg)
{
    int g = blockIdx.x * 256 + threadIdx.x;
    int wid = g >> 6;
    int lane = g & 63;
    int sub = lane >> 4;
    int l16 = lane & 15;
    int n = wid * 4 + sub;
    bool active = n < N_NODES;
    int o = 0, d = 0;
    if (active) { o = off[n]; d = deg[n]; }
    float acc[16];
    #pragma unroll
    for (int i = 0; i < 16; ++i) acc[i] = 0.0f;
    for (int p = 0; p < d; ++p) {
        int src = slots[o + p];
        uint4 v = *(const uint4*)(x + (size_t)src * 256 + l16 * 16);
        unsigned int uu[4] = {v.x, v.y, v.z, v.w};
        #pragma unroll
        for (int j = 0; j < 4; ++j)
            #pragma unroll
            for (int b = 0; b < 4; ++b)
                acc[j * 4 + b] += fp82f((uu[j] >> (8 * b)) & 0xffu);
    }
    if (active) {
        float rs = 1.0f / fmaxf((float)d, 1.0f);
        uint4 ov;
        ov.x = pack_fp8x4(acc[0] * rs,  acc[1] * rs,  acc[2] * rs,  acc[3] * rs);
        ov.y = pack_fp8x4(acc[4] * rs,  acc[5] * rs,  acc[6] * rs,  acc[7] * rs);
        ov.z = pack_fp8x4(acc[8] * rs,  acc[9] * rs,  acc[10] * rs, acc[11] * rs);
        ov.w = pack_fp8x4(acc[12] * rs, acc[13] * rs, acc[14] * rs, acc[15] * rs);
        *(uint4*)(agg + (size_t)n * 256 + l16 * 16) = ov;
    }
}

// ---------------------------------------------------------------------------
// SAGE layer, fp8 MFMA (R10 skeleton).  Swizzle key (r>>1)&3: drawn from
// bits disjoint with the bank-row bit r&1 -> 16 distinct bank-pairs per
// 64-lane ds_read_b64 = the b64 inherent minimum (~4M residual conflicts).
// 512 thr = 8 waves x 32 cols; tile 128x256, BK=64B; 3-buffer LDS,
// single barrier/step, steady vmcnt(1) ([stage(s), B(s)x4, stage(s+1)]).
// Out = relu([Agg8|X8] @ Wt8^T + bias) -> fp8 (row 256B).
// ---------------------------------------------------------------------------
__global__ __launch_bounds__(512, 4) void k_sage(
    const unsigned char* __restrict__ Agg8,
    const unsigned char* __restrict__ X8,
    const unsigned char* __restrict__ Wt8,
    const float* __restrict__ bias,
    unsigned char* __restrict__ Out)
{
    __shared__ char smem[32768];    // staging 3x8KB; epilogue tile reuse

    const int tid  = threadIdx.x;
    const int w    = tid >> 6, lane = tid & 63;
    const int l15  = lane & 15, lg = lane >> 4;
    const int row0 = blockIdx.x * 128;

    f32x4 acc[8][2];
    #pragma unroll
    for (int i = 0; i < 8; ++i)
        #pragma unroll
        for (int n = 0; n < 2; ++n) acc[i][n] = (f32x4)0.0f;

    // staging: 4 thr/row x 16B; row = tid>>2 (0..127), c16 = tid&3
    const int srow = tid >> 2;
    const int c16s = tid & 3;
    int sgrow = row0 + srow; if (sgrow >= N_NODES) sgrow = N_NODES - 1;
    const int skey = (srow >> 1) & 3;

    auto stage = [&](int s) {
        const int b = s % 3;
        const unsigned char* base = (s < 4) ? Agg8 : X8;
        int k0 = (s & 3) * 64;
        const unsigned char* gp = base + (size_t)sgrow * 256 + k0
                                + ((c16s ^ skey) << 4);         // inverse swizzle
        const char* lp = smem + b * 8192 + tid * 16;            // linear dest
        __builtin_amdgcn_global_load_lds(
            (const __attribute__((address_space(1))) void*)gp,
            (__attribute__((address_space(3))) void*)lp, 16, 0, 0);
    };

    auto loadB = [&](int s, i64v (&bb)[2][2]) {
        #pragma unroll
        for (int h = 0; h < 2; ++h)
            #pragma unroll
            for (int n = 0; n < 2; ++n) {
                int c = w * 32 + n * 16 + l15;
                bb[h][n] = *(const i64v*)(Wt8 + (size_t)c * 512 + s * 64
                                          + h * 32 + lg * 8);
            }
    };

    auto do_step = [&](int s, bool last, i64v (&bcur)[2][2], i64v (&bnxt)[2][2]) {
        const int b = s % 3;
        if (last) asm volatile("s_waitcnt vmcnt(0)" ::: "memory");
        else      asm volatile("s_waitcnt vmcnt(1)" ::: "memory");
        __builtin_amdgcn_sched_barrier(0);
        __builtin_amdgcn_s_barrier();
        __builtin_amdgcn_sched_barrier(0);
        if (!last) loadB(s + 1, bnxt);          // B prefetch for next step
        if (s + 2 < 8) stage(s + 2);            // 2-step-ahead A staging
        #pragma unroll
        for (int h = 0; h < 2; ++h) {
            const int c8 = h * 4 + lg;          // 8B chunk index 0..7
            #pragma unroll
            for (int i = 0; i < 8; ++i) {
                int r = i * 16 + l15;
                i64v a = *(const i64v*)(smem + b * 8192 + r * 64
                            + ((((c8 >> 1) ^ ((r >> 1) & 3)) << 4)
                               | ((c8 & 1) << 3)));
                acc[i][0] = __builtin_amdgcn_mfma_f32_16x16x32_fp8_fp8(
                    a, bcur[h][0], acc[i][0], 0, 0, 0);
                acc[i][1] = __builtin_amdgcn_mfma_f32_16x16x32_fp8_fp8(
                    a, bcur[h][1], acc[i][1], 0, 0, 0);
            }
        }
    };

    i64v b0[2][2], b1r[2][2];
    loadB(0, b0);       // queue: [B0 x4, st0, st1] -> vmcnt(1) at step 0 ok
    stage(0);
    stage(1);
    do_step(0, false, b0, b1r);
    do_step(1, false, b1r, b0);
    do_step(2, false, b0, b1r);
    do_step(3, false, b1r, b0);
    do_step(4, false, b0, b1r);
    do_step(5, false, b1r, b0);
    do_step(6, false, b0, b1r);
    do_step(7, true,  b1r, b0);

    __syncthreads();   // all waves done with staging before epilogue reuse
    unsigned char* lo = (unsigned char*)smem;     // 64x256 fp8 = 16KB half
    #pragma unroll
    for (int hh = 0; hh < 2; ++hh) {
        #pragma unroll
        for (int n = 0; n < 2; ++n) {
            int c = w * 32 + n * 16 + l15;
            float bv = bias[c];
            #pragma unroll
            for (int i2 = 0; i2 < 4; ++i2) {
                int i = hh * 4 + i2;
                #pragma unroll
                for (int r = 0; r < 4; ++r) {
                    int rl = i2 * 16 + lg * 4 + r;
                    lo[rl * 256 + c] = f2fp8(fmaxf(acc[i][n][r] + bv, 0.0f));
                }
            }
        }
        __syncthreads();
        #pragma unroll
        for (int q = 0; q < 2; ++q) {
            int chunk = tid + q * 512;      // 1024 x 16B = 64 rows x 256B
            int rl = chunk >> 4, cc = chunk & 15;
            int grow = row0 + hh * 64 + rl;
            if (grow < N_NODES)
                *(uint4*)(Out + (size_t)grow * 256 + cc * 16) =
                    *(const uint4*)((const char*)smem + rl * 256 + cc * 16);
        }
        __syncthreads();
    }
}

// ---------------------------------------------------------------------------
// HEAD, fp8: Pred += relu(X8 @ Wh8^T + b0) . W1  (K=256, 4 steps; same
// staging/swizzle as k_sage; Pred pre-init b1; atomicAdd partials).
// ---------------------------------------------------------------------------
__global__ __launch_bounds__(512, 4) void k_head8(
    const unsigned char* __restrict__ X8,
    const unsigned char* __restrict__ Wh8,
    const float* __restrict__ bias,
    const float* __restrict__ W1,
    float* __restrict__ Pred)
{
    __shared__ char smem[24576];    // 3x8KB staging

    const int tid  = threadIdx.x;
    const int w    = tid >> 6, lane = tid & 63;
    const int l15  = lane & 15, lg = lane >> 4;
    const int row0 = blockIdx.x * 128;

    f32x4 acc[8][2];
    #pragma unroll
    for (int i = 0; i < 8; ++i)
        #pragma unroll
        for (int n = 0; n < 2; ++n) acc[i][n] = (f32x4)0.0f;

    const int srow = tid >> 2;
    const int c16s = tid & 3;
    int sgrow = row0 + srow; if (sgrow >= N_NODES) sgrow = N_NODES - 1;
    const int skey = (srow >> 1) & 3;

    auto stage = [&](int s) {
        const int b = s % 3;
        const unsigned char* gp = X8 + (size_t)sgrow * 256 + s * 64
                                + ((c16s ^ skey) << 4);
        const char* lp = smem + b * 8192 + tid * 16;
        __builtin_amdgcn_global_load_lds(
            (const __attribute__((address_space(1))) void*)gp,
            (__attribute__((address_space(3))) void*)lp, 16, 0, 0);
    };

    auto loadB = [&](int s, i64v (&bb)[2][2]) {
        #pragma unroll
        for (int h = 0; h < 2; ++h)
            #pragma unroll
            for (int n = 0; n < 2; ++n) {
                int c = w * 32 + n * 16 + l15;
                bb[h][n] = *(const i64v*)(Wh8 + (size_t)c * 256 + s * 64
                                          + h * 32 + lg * 8);
            }
    };

    auto do_step = [&](int s, bool last, i64v (&bcur)[2][2], i64v (&bnxt)[2][2]) {
        const int b = s % 3;
        if (last) asm volatile("s_waitcnt vmcnt(0)" ::: "memory");
        else      asm volatile("s_waitcnt vmcnt(1)" ::: "memory");
        __builtin_amdgcn_sched_barrier(0);
        __builtin_amdgcn_s_barrier();
        __builtin_amdgcn_sched_barrier(0);
        if (!last) loadB(s + 1, bnxt);
        if (s + 2 < 4) stage(s + 2);
        #pragma unroll
        for (int h = 0; h < 2; ++h) {
            const int c8 = h * 4 + lg;
            #pragma unroll
            for (int i = 0; i < 8; ++i) {
                int r = i * 16 + l15;
                i64v a = *(const i64v*)(smem + b * 8192 + r * 64
                            + ((((c8 >> 1) ^ ((r >> 1) & 3)) << 4)
                               | ((c8 & 1) << 3)));
                acc[i][0] = __builtin_amdgcn_mfma_f32_16x16x32_fp8_fp8(
                    a, bcur[h][0], acc[i][0], 0, 0, 0);
                acc[i][1] = __builtin_amdgcn_mfma_f32_16x16x32_fp8_fp8(
                    a, bcur[h][1], acc[i][1], 0, 0, 0);
            }
        }
    };

    i64v b0[2][2], b1r[2][2];
    loadB(0, b0);
    stage(0);
    stage(1);
    do_step(0, false, b0, b1r);
    do_step(1, false, b1r, b0);
    do_step(2, false, b0, b1r);
    do_step(3, true,  b1r, b0);

    #pragma unroll
    for (int i = 0; i < 8; ++i) {
        float p[4];
        #pragma unroll
        for (int r = 0; r < 4; ++r) p[r] = 0.0f;
        #pragma unroll
        for (int n = 0; n < 2; ++n) {
            int cg = w * 32 + n * 16 + l15;
            float bv = bias[cg];
            float wv = W1[cg];
            #pragma unroll
            for (int r = 0; r < 4; ++r)
                p[r] += fmaxf(acc[i][n][r] + bv, 0.0f) * wv;
        }
        #pragma unroll
        for (int r = 0; r < 4; ++r) {
            float s = p[r];
            #pragma unroll
            for (int m = 1; m < 16; m <<= 1) s += __shfl_xor(s, m, 64);
            if (l15 == 0) {
                int row = row0 + i * 16 + lg * 4 + r;
                if (row < N_NODES) atomicAdd(&Pred[row], s);
            }
        }
    }
}

extern "C" void kernel_launch(void* const* d_in, const int* in_sizes, int n_in,
                              void* d_out, int out_size, void* d_ws, size_t ws_size,
                              hipStream_t stream) {
    const float* node_attr = (const float*)d_in[0];
    const float* y         = (const float*)d_in[1];
    const float* node_emb  = (const float*)d_in[2];
    const float* net_W     = (const float*)d_in[4];
    const float* net_b     = (const float*)d_in[5];
    const float* dev_W     = (const float*)d_in[6];
    const float* dev_b     = (const float*)d_in[7];
    const float* pin_emb   = (const float*)d_in[8];
    const float* sage_Wl   = (const float*)d_in[9];
    const float* sage_bl   = (const float*)d_in[10];
    const float* sage_Wr   = (const float*)d_in[11];
    const float* head_W0   = (const float*)d_in[12];
    const float* head_b0   = (const float*)d_in[13];
    const float* head_W1   = (const float*)d_in[14];
    const float* head_b1   = (const float*)d_in[15];
    const int*   node_type = (const int*)d_in[16];
    const int*   edge_idx  = (const int*)d_in[18];
    float* out = (float*)d_out;

    const size_t x8b = (size_t)N_NODES * 256;       // fp8 row bytes
    char* p = (char*)d_ws;
    unsigned char* x0   = (unsigned char*)p;  p += x8b;
    unsigned char* x1   = (unsigned char*)p;  p += x8b;
    unsigned char* agg8 = (unsigned char*)p;  p += x8b;
    unsigned char* Wt8  = (unsigned char*)p;  p += (size_t)3 * 256 * 512;
    unsigned char* Wh8  = (unsigned char*)p;  p += (size_t)256 * 256;
    int* deg    = (int*)p; p += N_NODES * 4;
    int* off    = (int*)p; p += N_NODES * 4;
    int* cursor = (int*)p; p += N_NODES * 4;
    int* slots  = (int*)p; p += N_EDGES * 4;
    int* total  = (int*)p; p += 16;

    k_prep<<<(3 * 131072 + 65536 + 255) / 256, 256, 0, stream>>>(
        sage_Wl, sage_Wr, head_W0, Wt8, Wh8, deg, total);
    k_init<<<(N_NODES * 17 + N_EDGES + 255) / 256, 256, 0, stream>>>(
        node_attr, node_emb, net_W, net_b, dev_W, dev_b, pin_emb, node_type,
        y, head_b1, edge_idx, deg, out, x0);
    k_alloc<<<(N_NODES + 255) / 256, 256, 0, stream>>>(deg, off, cursor, total);
    k_fill<<<(N_EDGES + 255) / 256, 256, 0, stream>>>(edge_idx, cursor, slots);

    const int agg_grid  = (N_NODES / 4 * 64 + 255) / 256;
    const int gemm_grid = (N_NODES + 127) / 128;
    // layer 1
    k_aggregate<<<agg_grid, 256, 0, stream>>>(x0, off, deg, slots, agg8);
    k_sage<<<gemm_grid, 512, 0, stream>>>(agg8, x0, Wt8, sage_bl, x1);
    // layer 2
    k_aggregate<<<agg_grid, 256, 0, stream>>>(x1, off, deg, slots, agg8);
    k_sage<<<gemm_grid, 512, 0, stream>>>(agg8, x1, Wt8 + 131072,
                                          sage_bl + HID, x0);
    // layer 3
    k_aggregate<<<agg_grid, 256, 0, stream>>>(x0, off, deg, slots, agg8);
    k_sage<<<gemm_grid, 512, 0, stream>>>(agg8, x0, Wt8 + 262144,
                                          sage_bl + 2 * HID, x1);
    // head
    k_head8<<<gemm_grid, 512, 0, stream>>>(x1, Wh8, head_b0, head_W1, out);
}

// Round 20
// 316.198 us; speedup vs baseline: 1.0970x; 1.0492x over previous
//
#include <hip/hip_runtime.h>
#include <hip/hip_bf16.h>
#include <hip/hip_fp8.h>

#define N_NODES 100000
#define N_EDGES 320000
#define HID 256
#define NE 128

typedef __attribute__((ext_vector_type(4))) float f32x4;
typedef __attribute__((ext_vector_type(2))) float f32x2;
typedef long long i64v;

// Native gfx950 fp8 (OCP e4m3) converts: single-instruction pack/unpack.
__device__ inline unsigned char f2fp8(float f) {
    return (unsigned char)(__builtin_amdgcn_cvt_pk_fp8_f32(f, f, 0, false) & 0xff);
}
__device__ inline float fp82f(unsigned char b) {
    return __builtin_amdgcn_cvt_f32_fp8((int)b, 0);
}
__device__ inline unsigned int pack_fp8x4(float a, float b, float c, float d) {
    int v = __builtin_amdgcn_cvt_pk_fp8_f32(a, b, 0, false);   // bytes 0,1
    v = __builtin_amdgcn_cvt_pk_fp8_f32(c, d, v, true);        // bytes 2,3
    return (unsigned int)v;
}

// ---------------------------------------------------------------------------
// Weight prep: sage + head weights fp32 -> fp8 [n][k].  Zeroes deg/total.
// ---------------------------------------------------------------------------
__global__ __launch_bounds__(256) void k_prep(
    const float* __restrict__ Wl, const float* __restrict__ Wr,
    const float* __restrict__ W0,
    unsigned char* __restrict__ Wt8, unsigned char* __restrict__ Wh8,
    int* __restrict__ deg, int* __restrict__ total)
{
    int t = blockIdx.x * 256 + threadIdx.x;
    const int total_sage = 3 * 256 * 512;
    if (t < total_sage) {
        int l = t >> 17;
        int rem = t & 131071;
        int n = rem >> 9;
        int k = rem & 511;
        const float* Wsrc = (k < 256) ? (Wl + (size_t)l * 65536)
                                      : (Wr + (size_t)l * 65536);
        Wt8[t] = f2fp8(Wsrc[(k & 255) * 256 + n]);
    } else {
        int u = t - total_sage;
        if (u < 65536) {
            int n = u >> 8, k = u & 255;
            Wh8[u] = f2fp8(W0[k * 256 + n]);
        }
    }
    if (t < N_NODES) deg[t] = 0;
    if (t == 0) *total = 0;
}

// ---------------------------------------------------------------------------
// Init: x0 in fp8 (row = 256B: [emb 0..127 | attr 128..255]).
// Weights staged in LDS; divergence-free 17-FMA loop; native fp8 packs.
// 16 thr/node x 8 cols, uint2 stores.  Tail ranges: output tail + histogram.
// ---------------------------------------------------------------------------
__global__ __launch_bounds__(256) void k_init(
    const float* __restrict__ node_attr,
    const float* __restrict__ node_emb,
    const float* __restrict__ net_W, const float* __restrict__ net_b,
    const float* __restrict__ dev_W, const float* __restrict__ dev_b,
    const float* __restrict__ pin_emb,
    const int*   __restrict__ node_type,
    const float* __restrict__ y, const float* __restrict__ b1,
    const int*   __restrict__ edge_index, int* __restrict__ deg,
    float* __restrict__ out,
    unsigned char* __restrict__ x)
{
    // LDS: net_W[17x128] | dev_W[17x128] | pin_emb[17x128] | node_emb[4x128]
    __shared__ float lds[7040];     // 28160 B
    {
        float4* d = (float4*)lds;
        for (int i = threadIdx.x; i < 544; i += 256)
            d[i] = ((const float4*)net_W)[i];
        for (int i = threadIdx.x; i < 544; i += 256)
            d[544 + i] = ((const float4*)dev_W)[i];
        for (int i = threadIdx.x; i < 544; i += 256)
            d[1088 + i] = ((const float4*)pin_emb)[i];
        for (int i = threadIdx.x; i < 128; i += 256)
            d[1632 + i] = ((const float4*)node_emb)[i];
    }
    __syncthreads();

    int t = blockIdx.x * 256 + threadIdx.x;
    if (t < N_NODES * 16) {
        int n  = t >> 4;
        int c8 = (t & 15) * 8;
        int c4 = c8 >> 2;
        int ty = node_type[n];
        const float4* ldsv = (const float4*)lds;

        float4 e0 = ldsv[1632 + ty * 32 + c4];
        float4 e1 = ldsv[1632 + ty * 32 + c4 + 1];

        const float* ar = node_attr + (size_t)n * 17;
        const float* bb = (ty == 1) ? dev_b : net_b;
        float4 a0 = *(const float4*)(bb + c8);
        float4 a1 = *(const float4*)(bb + c8 + 4);
        const int wb4 = (ty == 1) ? 544 : 0;    // float4 base of W in LDS
        #pragma unroll
        for (int k = 0; k < 17; ++k) {
            float av = ar[k];
            float4 w0 = ldsv[wb4 + k * 32 + c4];
            float4 w1 = ldsv[wb4 + k * 32 + c4 + 1];
            a0.x += av * w0.x; a0.y += av * w0.y;
            a0.z += av * w0.z; a0.w += av * w0.w;
            a1.x += av * w1.x; a1.y += av * w1.y;
            a1.z += av * w1.z; a1.w += av * w1.w;
        }
        if (ty == 2) {
            int idx = (int)ar[0];
            a0 = ldsv[1088 + idx * 32 + c4];
            a1 = ldsv[1088 + idx * 32 + c4 + 1];
        } else if (ty == 3) {
            a0.x = a0.y = a0.z = a0.w = 0.0f;
            a1 = a0;
        }

        uint2 ev = {pack_fp8x4(e0.x, e0.y, e0.z, e0.w),
                    pack_fp8x4(e1.x, e1.y, e1.z, e1.w)};
        uint2 av = {pack_fp8x4(a0.x, a0.y, a0.z, a0.w),
                    pack_fp8x4(a1.x, a1.y, a1.z, a1.w)};
        *(uint2*)(x + (size_t)n * 256 + c8)       = ev;
        *(uint2*)(x + (size_t)n * 256 + 128 + c8) = av;
    } else if (t < N_NODES * 17) {
        int n = t - N_NODES * 16;
        float y0 = y[(size_t)n * 2 + 0];
        float y1 = y[(size_t)n * 2 + 1];
        out[n] = b1[0];
        out[N_NODES + n] = (float)(int)y1;
        out[2 * N_NODES + 2 * n + 0] = y0;
        out[2 * N_NODES + 2 * n + 1] = y1;
    } else {
        int e = t - N_NODES * 17;
        if (e < N_EDGES) atomicAdd(&deg[edge_index[N_EDGES + e]], 1);
    }
}

// ---------------------------------------------------------------------------
// CSR build: scan-free chunk allocation -> fill
// ---------------------------------------------------------------------------
__global__ __launch_bounds__(256) void k_alloc(
    const int* __restrict__ deg, int* __restrict__ off,
    int* __restrict__ cursor, int* __restrict__ total)
{
    int n = blockIdx.x * 256 + threadIdx.x;
    int lane = threadIdx.x & 63;
    int d = (n < N_NODES) ? deg[n] : 0;
    int incl = d;
    #pragma unroll
    for (int o = 1; o < 64; o <<= 1) {
        int v = __shfl_up(incl, o, 64);
        if (lane >= o) incl += v;
    }
    int wtot = __shfl(incl, 63, 64);
    int base = 0;
    if (lane == 63) base = atomicAdd(total, wtot);
    base = __shfl(base, 63, 64);
    if (n < N_NODES) {
        int o = base + incl - d;
        off[n] = o;
        cursor[n] = o;
    }
}

__global__ __launch_bounds__(256) void k_fill(
    const int* __restrict__ edge_index, int* __restrict__ cursor,
    int* __restrict__ slots)
{
    int e = blockIdx.x * 256 + threadIdx.x;
    if (e >= N_EDGES) return;
    int s = edge_index[e];
    int d = edge_index[N_EDGES + e];
    int slot = atomicAdd(&cursor[d], 1);
    slots[slot] = s;
}

// ---------------------------------------------------------------------------
// Gather-mean over fp8 rows (256B): 4 nodes/wave, 16 lanes x 16B, fp32 acc.
// Native cvt_pk_f32_fp8 unpack: 8 instrs per 16B row chunk (was ~160 sw).
// ---------------------------------------------------------------------------
__global__ __launch_bounds__(256) void k_aggregate(
    const unsigned char* __restrict__ x,
    const int* __restrict__ off, const int* __restrict__ deg,
    const int* __restrict__ slots,
    unsigned char* __restrict__ agg)
{
    int g = blockIdx.x * 256 + threadIdx.x;
    int wid = g >> 6;
    int lane = g & 63;
    int sub = lane >> 4;
    int l16 = lane & 15;
    int n = wid * 4 + sub;
    bool active = n < N_NODES;
    int o = 0, d = 0;
    if (active) { o = off[n]; d = deg[n]; }
    float acc[16];
    #pragma unroll
    for (int i = 0; i < 16; ++i) acc[i] = 0.0f;
    for (int p = 0; p < d; ++p) {
        int src = slots[o + p];
        uint4 v = *(const uint4*)(x + (size_t)src * 256 + l16 * 16);
        unsigned int uu[4] = {v.x, v.y, v.z, v.w};
        #pragma unroll
        for (int j = 0; j < 4; ++j) {
            f32x2 lo = __builtin_amdgcn_cvt_pk_f32_fp8((int)uu[j], false);
            f32x2 hi = __builtin_amdgcn_cvt_pk_f32_fp8((int)uu[j], true);
            acc[j * 4 + 0] += lo.x;
            acc[j * 4 + 1] += lo.y;
            acc[j * 4 + 2] += hi.x;
            acc[j * 4 + 3] += hi.y;
        }
    }
    if (active) {
        float rs = 1.0f / fmaxf((float)d, 1.0f);
        uint4 ov;
        ov.x = pack_fp8x4(acc[0] * rs,  acc[1] * rs,  acc[2] * rs,  acc[3] * rs);
        ov.y = pack_fp8x4(acc[4] * rs,  acc[5] * rs,  acc[6] * rs,  acc[7] * rs);
        ov.z = pack_fp8x4(acc[8] * rs,  acc[9] * rs,  acc[10] * rs, acc[11] * rs);
        ov.w = pack_fp8x4(acc[12] * rs, acc[13] * rs, acc[14] * rs, acc[15] * rs);
        *(uint4*)(agg + (size_t)n * 256 + l16 * 16) = ov;
    }
}

// ---------------------------------------------------------------------------
// SAGE layer, fp8 MFMA (R10 skeleton).  Swizzle key (r>>1)&3: drawn from
// bits disjoint with the bank-row bit r&1 -> 16 distinct bank-pairs per
// 64-lane ds_read_b64 = the b64 inherent minimum (~4M residual conflicts).
// 512 thr = 8 waves x 32 cols; tile 128x256, BK=64B; 3-buffer LDS,
// single barrier/step, steady vmcnt(1) ([stage(s), B(s)x4, stage(s+1)]).
// Out = relu([Agg8|X8] @ Wt8^T + bias) -> fp8 (row 256B).
// ---------------------------------------------------------------------------
__global__ __launch_bounds__(512, 4) void k_sage(
    const unsigned char* __restrict__ Agg8,
    const unsigned char* __restrict__ X8,
    const unsigned char* __restrict__ Wt8,
    const float* __restrict__ bias,
    unsigned char* __restrict__ Out)
{
    __shared__ char smem[32768];    // staging 3x8KB; epilogue tile reuse

    const int tid  = threadIdx.x;
    const int w    = tid >> 6, lane = tid & 63;
    const int l15  = lane & 15, lg = lane >> 4;
    const int row0 = blockIdx.x * 128;

    f32x4 acc[8][2];
    #pragma unroll
    for (int i = 0; i < 8; ++i)
        #pragma unroll
        for (int n = 0; n < 2; ++n) acc[i][n] = (f32x4)0.0f;

    // staging: 4 thr/row x 16B; row = tid>>2 (0..127), c16 = tid&3
    const int srow = tid >> 2;
    const int c16s = tid & 3;
    int sgrow = row0 + srow; if (sgrow >= N_NODES) sgrow = N_NODES - 1;
    const int skey = (srow >> 1) & 3;

    auto stage = [&](int s) {
        const int b = s % 3;
        const unsigned char* base = (s < 4) ? Agg8 : X8;
        int k0 = (s & 3) * 64;
        const unsigned char* gp = base + (size_t)sgrow * 256 + k0
                                + ((c16s ^ skey) << 4);         // inverse swizzle
        const char* lp = smem + b * 8192 + tid * 16;            // linear dest
        __builtin_amdgcn_global_load_lds(
            (const __attribute__((address_space(1))) void*)gp,
            (__attribute__((address_space(3))) void*)lp, 16, 0, 0);
    };

    auto loadB = [&](int s, i64v (&bb)[2][2]) {
        #pragma unroll
        for (int h = 0; h < 2; ++h)
            #pragma unroll
            for (int n = 0; n < 2; ++n) {
                int c = w * 32 + n * 16 + l15;
                bb[h][n] = *(const i64v*)(Wt8 + (size_t)c * 512 + s * 64
                                          + h * 32 + lg * 8);
            }
    };

    auto do_step = [&](int s, bool last, i64v (&bcur)[2][2], i64v (&bnxt)[2][2]) {
        const int b = s % 3;
        if (last) asm volatile("s_waitcnt vmcnt(0)" ::: "memory");
        else      asm volatile("s_waitcnt vmcnt(1)" ::: "memory");
        __builtin_amdgcn_sched_barrier(0);
        __builtin_amdgcn_s_barrier();
        __builtin_amdgcn_sched_barrier(0);
        if (!last) loadB(s + 1, bnxt);          // B prefetch for next step
        if (s + 2 < 8) stage(s + 2);            // 2-step-ahead A staging
        #pragma unroll
        for (int h = 0; h < 2; ++h) {
            const int c8 = h * 4 + lg;          // 8B chunk index 0..7
            #pragma unroll
            for (int i = 0; i < 8; ++i) {
                int r = i * 16 + l15;
                i64v a = *(const i64v*)(smem + b * 8192 + r * 64
                            + ((((c8 >> 1) ^ ((r >> 1) & 3)) << 4)
                               | ((c8 & 1) << 3)));
                acc[i][0] = __builtin_amdgcn_mfma_f32_16x16x32_fp8_fp8(
                    a, bcur[h][0], acc[i][0], 0, 0, 0);
                acc[i][1] = __builtin_amdgcn_mfma_f32_16x16x32_fp8_fp8(
                    a, bcur[h][1], acc[i][1], 0, 0, 0);
            }
        }
    };

    i64v b0[2][2], b1r[2][2];
    loadB(0, b0);       // queue: [B0 x4, st0, st1] -> vmcnt(1) at step 0 ok
    stage(0);
    stage(1);
    do_step(0, false, b0, b1r);
    do_step(1, false, b1r, b0);
    do_step(2, false, b0, b1r);
    do_step(3, false, b1r, b0);
    do_step(4, false, b0, b1r);
    do_step(5, false, b1r, b0);
    do_step(6, false, b0, b1r);
    do_step(7, true,  b1r, b0);

    __syncthreads();   // all waves done with staging before epilogue reuse
    unsigned char* lo = (unsigned char*)smem;     // 64x256 fp8 = 16KB half
    #pragma unroll
    for (int hh = 0; hh < 2; ++hh) {
        #pragma unroll
        for (int n = 0; n < 2; ++n) {
            int c = w * 32 + n * 16 + l15;
            float bv = bias[c];
            #pragma unroll
            for (int i2 = 0; i2 < 4; ++i2) {
                int i = hh * 4 + i2;
                #pragma unroll
                for (int r = 0; r < 4; ++r) {
                    int rl = i2 * 16 + lg * 4 + r;
                    lo[rl * 256 + c] = f2fp8(fmaxf(acc[i][n][r] + bv, 0.0f));
                }
            }
        }
        __syncthreads();
        #pragma unroll
        for (int q = 0; q < 2; ++q) {
            int chunk = tid + q * 512;      // 1024 x 16B = 64 rows x 256B
            int rl = chunk >> 4, cc = chunk & 15;
            int grow = row0 + hh * 64 + rl;
            if (grow < N_NODES)
                *(uint4*)(Out + (size_t)grow * 256 + cc * 16) =
                    *(const uint4*)((const char*)smem + rl * 256 + cc * 16);
        }
        __syncthreads();
    }
}

// ---------------------------------------------------------------------------
// HEAD, fp8: Pred += relu(X8 @ Wh8^T + b0) . W1  (K=256, 4 steps; same
// staging/swizzle as k_sage; Pred pre-init b1; atomicAdd partials).
// ---------------------------------------------------------------------------
__global__ __launch_bounds__(512, 4) void k_head8(
    const unsigned char* __restrict__ X8,
    const unsigned char* __restrict__ Wh8,
    const float* __restrict__ bias,
    const float* __restrict__ W1,
    float* __restrict__ Pred)
{
    __shared__ char smem[24576];    // 3x8KB staging

    const int tid  = threadIdx.x;
    const int w    = tid >> 6, lane = tid & 63;
    const int l15  = lane & 15, lg = lane >> 4;
    const int row0 = blockIdx.x * 128;

    f32x4 acc[8][2];
    #pragma unroll
    for (int i = 0; i < 8; ++i)
        #pragma unroll
        for (int n = 0; n < 2; ++n) acc[i][n] = (f32x4)0.0f;

    const int srow = tid >> 2;
    const int c16s = tid & 3;
    int sgrow = row0 + srow; if (sgrow >= N_NODES) sgrow = N_NODES - 1;
    const int skey = (srow >> 1) & 3;

    auto stage = [&](int s) {
        const int b = s % 3;
        const unsigned char* gp = X8 + (size_t)sgrow * 256 + s * 64
                                + ((c16s ^ skey) << 4);
        const char* lp = smem + b * 8192 + tid * 16;
        __builtin_amdgcn_global_load_lds(
            (const __attribute__((address_space(1))) void*)gp,
            (__attribute__((address_space(3))) void*)lp, 16, 0, 0);
    };

    auto loadB = [&](int s, i64v (&bb)[2][2]) {
        #pragma unroll
        for (int h = 0; h < 2; ++h)
            #pragma unroll
            for (int n = 0; n < 2; ++n) {
                int c = w * 32 + n * 16 + l15;
                bb[h][n] = *(const i64v*)(Wh8 + (size_t)c * 256 + s * 64
                                          + h * 32 + lg * 8);
            }
    };

    auto do_step = [&](int s, bool last, i64v (&bcur)[2][2], i64v (&bnxt)[2][2]) {
        const int b = s % 3;
        if (last) asm volatile("s_waitcnt vmcnt(0)" ::: "memory");
        else      asm volatile("s_waitcnt vmcnt(1)" ::: "memory");
        __builtin_amdgcn_sched_barrier(0);
        __builtin_amdgcn_s_barrier();
        __builtin_amdgcn_sched_barrier(0);
        if (!last) loadB(s + 1, bnxt);
        if (s + 2 < 4) stage(s + 2);
        #pragma unroll
        for (int h = 0; h < 2; ++h) {
            const int c8 = h * 4 + lg;
            #pragma unroll
            for (int i = 0; i < 8; ++i) {
                int r = i * 16 + l15;
                i64v a = *(const i64v*)(smem + b * 8192 + r * 64
                            + ((((c8 >> 1) ^ ((r >> 1) & 3)) << 4)
                               | ((c8 & 1) << 3)));
                acc[i][0] = __builtin_amdgcn_mfma_f32_16x16x32_fp8_fp8(
                    a, bcur[h][0], acc[i][0], 0, 0, 0);
                acc[i][1] = __builtin_amdgcn_mfma_f32_16x16x32_fp8_fp8(
                    a, bcur[h][1], acc[i][1], 0, 0, 0);
            }
        }
    };

    i64v b0[2][2], b1r[2][2];
    loadB(0, b0);
    stage(0);
    stage(1);
    do_step(0, false, b0, b1r);
    do_step(1, false, b1r, b0);
    do_step(2, false, b0, b1r);
    do_step(3, true,  b1r, b0);

    #pragma unroll
    for (int i = 0; i < 8; ++i) {
        float p[4];
        #pragma unroll
        for (int r = 0; r < 4; ++r) p[r] = 0.0f;
        #pragma unroll
        for (int n = 0; n < 2; ++n) {
            int cg = w * 32 + n * 16 + l15;
            float bv = bias[cg];
            float wv = W1[cg];
            #pragma unroll
            for (int r = 0; r < 4; ++r)
                p[r] += fmaxf(acc[i][n][r] + bv, 0.0f) * wv;
        }
        #pragma unroll
        for (int r = 0; r < 4; ++r) {
            float s = p[r];
            #pragma unroll
            for (int m = 1; m < 16; m <<= 1) s += __shfl_xor(s, m, 64);
            if (l15 == 0) {
                int row = row0 + i * 16 + lg * 4 + r;
                if (row < N_NODES) atomicAdd(&Pred[row], s);
            }
        }
    }
}

extern "C" void kernel_launch(void* const* d_in, const int* in_sizes, int n_in,
                              void* d_out, int out_size, void* d_ws, size_t ws_size,
                              hipStream_t stream) {
    const float* node_attr = (const float*)d_in[0];
    const float* y         = (const float*)d_in[1];
    const float* node_emb  = (const float*)d_in[2];
    const float* net_W     = (const float*)d_in[4];
    const float* net_b     = (const float*)d_in[5];
    const float* dev_W     = (const float*)d_in[6];
    const float* dev_b     = (const float*)d_in[7];
    const float* pin_emb   = (const float*)d_in[8];
    const float* sage_Wl   = (const float*)d_in[9];
    const float* sage_bl   = (const float*)d_in[10];
    const float* sage_Wr   = (const float*)d_in[11];
    const float* head_W0   = (const float*)d_in[12];
    const float* head_b0   = (const float*)d_in[13];
    const float* head_W1   = (const float*)d_in[14];
    const float* head_b1   = (const float*)d_in[15];
    const int*   node_type = (const int*)d_in[16];
    const int*   edge_idx  = (const int*)d_in[18];
    float* out = (float*)d_out;

    const size_t x8b = (size_t)N_NODES * 256;       // fp8 row bytes
    char* p = (char*)d_ws;
    unsigned char* x0   = (unsigned char*)p;  p += x8b;
    unsigned char* x1   = (unsigned char*)p;  p += x8b;
    unsigned char* agg8 = (unsigned char*)p;  p += x8b;
    unsigned char* Wt8  = (unsigned char*)p;  p += (size_t)3 * 256 * 512;
    unsigned char* Wh8  = (unsigned char*)p;  p += (size_t)256 * 256;
    int* deg    = (int*)p; p += N_NODES * 4;
    int* off    = (int*)p; p += N_NODES * 4;
    int* cursor = (int*)p; p += N_NODES * 4;
    int* slots  = (int*)p; p += N_EDGES * 4;
    int* total  = (int*)p; p += 16;

    k_prep<<<(3 * 131072 + 65536 + 255) / 256, 256, 0, stream>>>(
        sage_Wl, sage_Wr, head_W0, Wt8, Wh8, deg, total);
    k_init<<<(N_NODES * 17 + N_EDGES + 255) / 256, 256, 0, stream>>>(
        node_attr, node_emb, net_W, net_b, dev_W, dev_b, pin_emb, node_type,
        y, head_b1, edge_idx, deg, out, x0);
    k_alloc<<<(N_NODES + 255) / 256, 256, 0, stream>>>(deg, off, cursor, total);
    k_fill<<<(N_EDGES + 255) / 256, 256, 0, stream>>>(edge_idx, cursor, slots);

    const int agg_grid  = (N_NODES / 4 * 64 + 255) / 256;
    const int gemm_grid = (N_NODES + 127) / 128;
    // layer 1
    k_aggregate<<<agg_grid, 256, 0, stream>>>(x0, off, deg, slots, agg8);
    k_sage<<<gemm_grid, 512, 0, stream>>>(agg8, x0, Wt8, sage_bl, x1);
    // layer 2
    k_aggregate<<<agg_grid, 256, 0, stream>>>(x1, off, deg, slots, agg8);
    k_sage<<<gemm_grid, 512, 0, stream>>>(agg8, x1, Wt8 + 131072,
                                          sage_bl + HID, x0);
    // layer 3
    k_aggregate<<<agg_grid, 256, 0, stream>>>(x0, off, deg, slots, agg8);
    k_sage<<<gemm_grid, 512, 0, stream>>>(agg8, x0, Wt8 + 262144,
                                          sage_bl + 2 * HID, x1);
    // head
    k_head8<<<gemm_grid, 512, 0, stream>>>(x1, Wh8, head_b0, head_W1, out);
}